// Round 3
// baseline (1043.855 us; speedup 1.0000x reference)
//
#include <hip/hip_runtime.h>
#include <hip/hip_bf16.h>
#include <hip/hip_fp16.h>

// Problem: y[b,s,o] = sum_i x[b,s,i] * w[o,i] + bias[o]
//   w = weight_high + fp32(weight_medium) + (~high & ~medium) * weight_low * low_scale
// M = 4*2048 = 8192, N = 4096, K = 4096.
// Round 3: the LDS pipe was co-critical (96 ds_read_b128/K-tile ~= MFMA cycles),
// and barrier-lockstep serialized the two bursts (measured 47-49% MfmaUtil).
// Fix: A-operand bypasses LDS entirely -- global->VGPR fragment loads (coalesced,
// 16 rows x 64B segments, x4 CU redundancy absorbed by L1), double-buffered one
// tile ahead (static reg names afX/afY). Only B is staged in LDS (4 x 16KB bufs,
// counted vmcnt, XOR swizzle). LDS reads/K-tile drop 96KB -> 32KB.

#define M_DIM 8192
#define N_DIM 4096
#define K_DIM 4096

typedef __attribute__((ext_vector_type(8))) short short8;
typedef __attribute__((ext_vector_type(4))) float floatx4;
typedef __attribute__((ext_vector_type(8))) _Float16 half8;
typedef __attribute__((ext_vector_type(8))) unsigned char uchar8;
typedef __attribute__((ext_vector_type(4))) int intx4;

__device__ inline unsigned short f2bf(float f) {
    union { float f; unsigned u; } v; v.f = f;
    return (unsigned short)((v.u + 0x7fffu + ((v.u >> 16) & 1u)) >> 16);  // RNE
}

__device__ inline void async16(const void* g, const void* l) {
    __builtin_amdgcn_global_load_lds(
        (const __attribute__((address_space(1))) void*)g,
        (__attribute__((address_space(3))) void*)l,
        16, 0, 0);
}

// ---------- fused prep: dtype-detect (per-block ballot) + w reconstruct + x cvt ----------
// blocks [0, 8192)        : wbf[i] = bf16(wh + wm + lowmask*wl*scale), 8 elems/thread
// blocks [8192, 24576)    : xbf[i] = bf16(x[i]), 8 elems/thread
__global__ __launch_bounds__(256) void prep_kernel(
        const float* __restrict__ x,
        const float* __restrict__ wh, const void* __restrict__ wm_raw,
        const int* __restrict__ wl, const void* __restrict__ hm_raw,
        const void* __restrict__ mm_raw, const float* __restrict__ scale_p,
        unsigned short* __restrict__ wbf, unsigned short* __restrict__ xbf) {
    const int bid = blockIdx.x;
    const int tid = threadIdx.x;

    if (bid >= 8192) {
        const size_t i = ((size_t)(bid - 8192) * 256 + tid) * 8;
        floatx4 f0 = *(const floatx4*)(x + i);
        floatx4 f1 = *(const floatx4*)(x + i + 4);
        short8 s;
        s[0] = (short)f2bf(f0[0]); s[1] = (short)f2bf(f0[1]);
        s[2] = (short)f2bf(f0[2]); s[3] = (short)f2bf(f0[3]);
        s[4] = (short)f2bf(f1[0]); s[5] = (short)f2bf(f1[1]);
        s[6] = (short)f2bf(f1[2]); s[7] = (short)f2bf(f1[3]);
        *(short8*)(xbf + i) = s;
        return;
    }

    // dtype flags from the first 64 words (L2 broadcast, per-block ballot)
    const int lane = tid & 63;
    union { unsigned u; float f; } pw; pw.u = ((const unsigned*)wm_raw)[lane];
    const float pav = fabsf(pw.f);
    const bool wm_f32  = __popcll(__ballot(pav > 1e-4f && pav < 1.0f)) >= 4;
    const bool mask_u8 = __ballot(((const unsigned*)hm_raw)[lane] > 1u) != 0;

    const size_t i = ((size_t)bid * 256 + tid) * 8;
    const float scale = *scale_p;

    floatx4 h0 = *(const floatx4*)(wh + i);
    floatx4 h1 = *(const floatx4*)(wh + i + 4);
    intx4  l0 = *(const intx4*)(wl + i);
    intx4  l1 = *(const intx4*)(wl + i + 4);

    float mv[8];
    if (wm_f32) {
        floatx4 m0 = *(const floatx4*)((const float*)wm_raw + i);
        floatx4 m1 = *(const floatx4*)((const float*)wm_raw + i + 4);
#pragma unroll
        for (int e = 0; e < 4; ++e) { mv[e] = m0[e]; mv[e + 4] = m1[e]; }
    } else {
        half8 m = *(const half8*)((const _Float16*)wm_raw + i);
#pragma unroll
        for (int e = 0; e < 8; ++e) mv[e] = (float)m[e];
    }

    int lowmask[8];
    if (mask_u8) {
        uchar8 a = *(const uchar8*)((const unsigned char*)hm_raw + i);
        uchar8 b = *(const uchar8*)((const unsigned char*)mm_raw + i);
#pragma unroll
        for (int e = 0; e < 8; ++e) lowmask[e] = (a[e] | b[e]) == 0;
    } else {
        intx4 a0 = *(const intx4*)((const int*)hm_raw + i);
        intx4 a1 = *(const intx4*)((const int*)hm_raw + i + 4);
        intx4 b0 = *(const intx4*)((const int*)mm_raw + i);
        intx4 b1 = *(const intx4*)((const int*)mm_raw + i + 4);
#pragma unroll
        for (int e = 0; e < 4; ++e) {
            lowmask[e]     = (a0[e] | b0[e]) == 0;
            lowmask[e + 4] = (a1[e] | b1[e]) == 0;
        }
    }

    short8 s;
#pragma unroll
    for (int e = 0; e < 8; ++e) {
        float v = (e < 4 ? h0[e] : h1[e - 4]) + mv[e];
        int   lw = (e < 4 ? l0[e] : l1[e - 4]);
        if (lowmask[e]) v += (float)lw * scale;
        s[e] = (short)f2bf(v);
    }
    *(short8*)(wbf + i) = s;
}

// ---------- 256x256 GEMM: A global->reg (depth-2), B LDS-staged (depth-3) ----------
// C[m,n] = sum_k A[m,k]*B[n,k] + bias[n] (A,B bf16 row-major [*,K], C fp32)
// 512 threads = 8 waves (2M x 4N); per-wave output 128x64.
// LDS: 4 B-buffers x 16 KiB = 64 KiB dynamic.
// Per-thread per-iter VMEM issue order: A(t+1) x8 (global b128 -> regs),
// B-stage(t+3) x2 (async16). Steady state: WAITV(2) at top of iter t drains
// A(t) [and B(t+1)]; B(t) drained one iter earlier; top barrier publishes it.
// Stage(t+3) -> buf[(t-1)&3], issued after the barrier that postdates all
// waves' ds_reads of tile t-1 (same clobber proof as rounds 1-2).
__global__ __launch_bounds__(512, 2) void gemm256_kernel(
        const unsigned short* __restrict__ A,   // [M,K] bf16
        const unsigned short* __restrict__ Bw,  // [N,K] bf16
        const float* __restrict__ bias,
        float* __restrict__ out) {
    extern __shared__ char smem[];
    const int tid  = threadIdx.x;
    const int wave = tid >> 6, lane = tid & 63;
    const int lrow = lane & 15, lquad = lane >> 4;

    // XCD-bijective swizzle: 512 blocks, 64 per XCD; bn varies fastest within
    // an XCD so co-resident blocks share the A panel in L2.
    const int wg  = blockIdx.x;
    const int swz = (wg & 7) * 64 + (wg >> 3);
    const int bm0 = (swz >> 4) * 256;   // 32 row-tiles
    const int bn0 = (swz & 15) * 256;   // 16 col-tiles

    const int wr = wave >> 2, wc = wave & 3;
    const int wm = wr * 128, wn = wc * 64;

    // B staging: linear LDS dest, pre-swizzled per-lane global source
    const int lane2 = lane ^ ((lane & 32) ? 2 : 0);
    const int srow  = wave * 16 + (lane2 >> 2);   // 0..127
    const int scol  = (lane2 & 3) * 8;            // 0,8,16,24
    const unsigned short* gB0 = Bw + (size_t)(bn0 + srow) * K_DIM + scol;
    const unsigned short* gB1 = gB0 + (size_t)128 * K_DIM;
    const int dstB = wave * 1024;   // wave-uniform LDS byte offset

    // swizzled LDS read byte offsets for B (within a 16 KiB buffer)
    int offB[4];
#pragma unroll
    for (int j = 0; j < 4; ++j) {
        int q = (wn + j * 16 + lrow) * 64 + lquad * 16;
        offB[j] = q ^ (((q >> 9) & 1) << 5);
    }

    // A fragment base: lane reads A[bm0+wm+i*16+lrow][t*32 + lquad*8 .. +8]
    const unsigned short* pa = A + (size_t)(bm0 + wm + lrow) * K_DIM + lquad * 8;

    floatx4 acc[8][4] = {};
    short8 afX[8], afY[8];
    short8 bq[4];

#define APREF(AF, T) do { \
        _Pragma("unroll") \
        for (int i_ = 0; i_ < 8; ++i_) \
            AF[i_] = *(const short8*)(pa + (size_t)i_ * 16 * K_DIM + (size_t)(T) * 32); \
    } while (0)

#define BSTAGE(T) do { \
        char* d_ = smem + ((T) & 3) * 16384 + dstB; \
        const unsigned ko_ = (unsigned)(T) * 32u; \
        async16(gB0 + ko_, d_); async16(gB1 + ko_, d_ + 8192); } while (0)

#define BREAD(T) do { \
        const char* b_ = smem + ((T) & 3) * 16384; \
        _Pragma("unroll") \
        for (int j_ = 0; j_ < 4; ++j_) bq[j_] = *(const short8*)(b_ + offB[j_]); \
    } while (0)

#define MMA(AF) do { \
        __builtin_amdgcn_s_setprio(1); \
        _Pragma("unroll") \
        for (int i_ = 0; i_ < 8; ++i_) \
            _Pragma("unroll") \
            for (int j_ = 0; j_ < 4; ++j_) \
                acc[i_][j_] = __builtin_amdgcn_mfma_f32_16x16x32_bf16(AF[i_], bq[j_], acc[i_][j_], 0, 0, 0); \
        __builtin_amdgcn_s_setprio(0); } while (0)

#define WAITV(n) asm volatile("s_waitcnt vmcnt(" #n ")" ::: "memory")
#define BAR() do { __builtin_amdgcn_s_barrier(); asm volatile("" ::: "memory"); } while (0)
#define SCHED0() __builtin_amdgcn_sched_barrier(0)

// One barrier per K-tile. ds_reads for the critical path first, then the
// A-prefetch + B-stage issue burst, then SCHED0 pins them before the MFMAs.
#define ITER(T, AFC, AFN, DOB) do { \
        WAITV(2); \
        BAR(); \
        BREAD(T); \
        APREF(AFN, (T) + 1); \
        if (DOB) BSTAGE((T) + 3); \
        SCHED0(); \
        MMA(AFC); } while (0)

    // prologue: A(0) -> afX (8 loads), B(0..2) staged (6 async16) = 14 in flight
    APREF(afX, 0);
    BSTAGE(0); BSTAGE(1); BSTAGE(2);

    const int NT = K_DIM / 32;  // 128
    // main: t = 0..123 paired (static afX/afY alternation), then 4 peeled iters
    for (int t = 0; t < NT - 4; t += 2) {
        ITER(t,     afX, afY, true);
        ITER(t + 1, afY, afX, true);
    }
    ITER(NT - 4, afX, afY, true);    // t=124, stages B(127)
    ITER(NT - 3, afY, afX, false);   // t=125, prefetches A(126)
    // t = 126: outstanding [B(127)x2, A(126)x8] -> need A(126): drain all
    WAITV(0); BAR(); BREAD(NT - 2); APREF(afY, NT - 1); SCHED0(); MMA(afX);
    // t = 127: outstanding [A(127)x8]
    WAITV(0); BAR(); BREAD(NT - 1); SCHED0(); MMA(afY);

#undef APREF
#undef BSTAGE
#undef BREAD
#undef MMA
#undef WAITV
#undef BAR
#undef SCHED0
#undef ITER

    // epilogue (verified 16x16 C/D layout: col = lane&15, row = lquad*4 + r)
#pragma unroll
    for (int j = 0; j < 4; ++j) {
        const int col = bn0 + wn + j * 16 + lrow;
        const float bv = bias[col];
#pragma unroll
        for (int i = 0; i < 8; ++i) {
            const int row = bm0 + wm + i * 16 + lquad * 4;
#pragma unroll
            for (int r = 0; r < 4; ++r)
                out[(size_t)(row + r) * N_DIM + col] = acc[i][j][r] + bv;
        }
    }
}

// ---------- fallback: A staged from fp32 inline (small-ws path) ----------
__global__ __launch_bounds__(256) void gemm_fused_kernel(
        const float* __restrict__ X,            // [M,K] fp32
        const unsigned short* __restrict__ Bw,  // [N,K] bf16
        const float* __restrict__ bias,
        float* __restrict__ out) {
    __shared__ unsigned short As[128 * 32];
    __shared__ unsigned short Bs[128 * 32];
    const int tid  = threadIdx.x;
    const int wave = tid >> 6, lane = tid & 63;
    const int bm0 = blockIdx.y * 128, bn0 = blockIdx.x * 128;
    const int wm = (wave >> 1) * 64, wn = (wave & 1) * 64;
    const int lrow = lane & 15, lquad = lane >> 4;
    const int arow = tid >> 1, acol = (tid & 1) * 16;

    floatx4 acc[4][4] = {};

    for (int k0 = 0; k0 < K_DIM; k0 += 32) {
        __syncthreads();
#pragma unroll
        for (int c = 0; c < 2; ++c) {
            const int lb  = wave * 2048 + c * 1024;
            const int e   = (lb >> 1) + lane * 8;
            const int row = e >> 5, col = e & 31;
            async16(Bw + (size_t)(bn0 + row) * K_DIM + k0 + col, (const char*)Bs + lb);
        }
        {
            const float* g = X + (size_t)(bm0 + arow) * K_DIM + k0 + acol;
            floatx4 f0 = *(const floatx4*)(g);
            floatx4 f1 = *(const floatx4*)(g + 4);
            floatx4 f2 = *(const floatx4*)(g + 8);
            floatx4 f3 = *(const floatx4*)(g + 12);
            short8 s0, s1;
            s0[0]=(short)f2bf(f0[0]); s0[1]=(short)f2bf(f0[1]); s0[2]=(short)f2bf(f0[2]); s0[3]=(short)f2bf(f0[3]);
            s0[4]=(short)f2bf(f1[0]); s0[5]=(short)f2bf(f1[1]); s0[6]=(short)f2bf(f1[2]); s0[7]=(short)f2bf(f1[3]);
            s1[0]=(short)f2bf(f2[0]); s1[1]=(short)f2bf(f2[1]); s1[2]=(short)f2bf(f2[2]); s1[3]=(short)f2bf(f2[3]);
            s1[4]=(short)f2bf(f3[0]); s1[5]=(short)f2bf(f3[1]); s1[6]=(short)f2bf(f3[2]); s1[7]=(short)f2bf(f3[3]);
            *(short8*)&As[arow * 32 + acol]     = s0;
            *(short8*)&As[arow * 32 + acol + 8] = s1;
        }
        __syncthreads();

        short8 af[4], bf[4];
#pragma unroll
        for (int i = 0; i < 4; ++i)
            af[i] = *(const short8*)&As[(wm + i * 16 + lrow) * 32 + lquad * 8];
#pragma unroll
        for (int j = 0; j < 4; ++j)
            bf[j] = *(const short8*)&Bs[(wn + j * 16 + lrow) * 32 + lquad * 8];
#pragma unroll
        for (int i = 0; i < 4; ++i)
#pragma unroll
            for (int j = 0; j < 4; ++j)
                acc[i][j] = __builtin_amdgcn_mfma_f32_16x16x32_bf16(af[i], bf[j], acc[i][j], 0, 0, 0);
    }

#pragma unroll
    for (int j = 0; j < 4; ++j) {
        const int col = bn0 + wn + j * 16 + lrow;
        const float bv = bias[col];
#pragma unroll
        for (int i = 0; i < 4; ++i) {
            const int row = bm0 + wm + i * 16 + lquad * 4;
#pragma unroll
            for (int r = 0; r < 4; ++r)
                out[(size_t)(row + r) * N_DIM + col] = acc[i][j][r] + bv;
        }
    }
}

extern "C" void kernel_launch(void* const* d_in, const int* in_sizes, int n_in,
                              void* d_out, int out_size, void* d_ws, size_t ws_size,
                              hipStream_t stream) {
    const float*    x     = (const float*)d_in[0];
    const float*    wh    = (const float*)d_in[1];
    const void*     wmed  = d_in[2];           // fp32 or fp16 — detected on device
    const int*      wl    = (const int*)d_in[3];
    const void*     hm    = d_in[4];           // int32 or uint8 — detected on device
    const void*     mm    = d_in[5];
    const float*    scale = (const float*)d_in[6];
    const float*    bias  = (const float*)d_in[7];
    float*          out   = (float*)d_out;

    unsigned short* wbf   = (unsigned short*)((char*)d_ws + 256);         // 32 MB
    unsigned short* xbf   = (unsigned short*)((char*)d_ws + 256 + (size_t)N_DIM * K_DIM * 2);
    const size_t need_full = 256 + (size_t)N_DIM * K_DIM * 2 + (size_t)M_DIM * K_DIM * 2;

    static bool attr_done = false;
    if (!attr_done) {
        (void)hipFuncSetAttribute(reinterpret_cast<const void*>(gemm256_kernel),
                                  hipFuncAttributeMaxDynamicSharedMemorySize, 65536);
        attr_done = true;
    }

    if (ws_size >= need_full) {
        // one fused prep launch: blocks [0,8192) build w, [8192,24576) convert x
        prep_kernel<<<24576, 256, 0, stream>>>(x, wh, wmed, wl, hm, mm, scale, wbf, xbf);
        gemm256_kernel<<<dim3(512), dim3(512), 65536, stream>>>(xbf, wbf, bias, out);
    } else {
        prep_kernel<<<8192, 256, 0, stream>>>(x, wh, wmed, wl, hm, mm, scale, wbf, wbf);
        dim3 grid(N_DIM / 128, M_DIM / 128);
        gemm_fused_kernel<<<grid, 256, 0, stream>>>(x, wbf, bias, out);
    }
}

// Round 4
// 662.639 us; speedup vs baseline: 1.5753x; 1.5753x over previous
//
#include <hip/hip_runtime.h>
#include <hip/hip_bf16.h>
#include <hip/hip_fp16.h>

// Problem: y[b,s,o] = sum_i x[b,s,i] * w[o,i] + bias[o]
//   w = weight_high + fp32(weight_medium) + (~high & ~medium) * weight_low * low_scale
// M = 4*2048 = 8192, N = 4096, K = 4096.
// Round 4: revert round-3's A-global-reg (latency disaster, 17% MfmaUtil).
// Back to round-1 structure (both operands LDS-staged, 4 x 32KB buffers,
// counted vmcnt, 1 barrier/tile) + NEW: ds_reads pipelined ONE TILE AHEAD.
// Iter t: MFMA(t) waits lgkmcnt(12) -- only the older read set -- while
// reads(t+1) (issued this iter into the alternate register set) drain on the
// LDS pipe UNDER the MFMA burst. This overlaps the two per-CU pipes
// (LDS ~1150 cy/tile, MFMA ~1242 cy/tile) that previously serialized.

#define M_DIM 8192
#define N_DIM 4096
#define K_DIM 4096

typedef __attribute__((ext_vector_type(8))) short short8;
typedef __attribute__((ext_vector_type(4))) float floatx4;
typedef __attribute__((ext_vector_type(8))) _Float16 half8;
typedef __attribute__((ext_vector_type(8))) unsigned char uchar8;
typedef __attribute__((ext_vector_type(4))) int intx4;

__device__ inline unsigned short f2bf(float f) {
    union { float f; unsigned u; } v; v.f = f;
    return (unsigned short)((v.u + 0x7fffu + ((v.u >> 16) & 1u)) >> 16);  // RNE
}

__device__ inline void async16(const void* g, const void* l) {
    __builtin_amdgcn_global_load_lds(
        (const __attribute__((address_space(1))) void*)g,
        (__attribute__((address_space(3))) void*)l,
        16, 0, 0);
}

// ---------- fused prep: dtype-detect (per-block ballot) + w reconstruct + x cvt ----------
// blocks [0, 8192)     : wbf[i] = bf16(wh + wm + lowmask*wl*scale), 8 elems/thread
// blocks [8192, 24576) : xbf[i] = bf16(x[i]), 8 elems/thread
__global__ __launch_bounds__(256) void prep_kernel(
        const float* __restrict__ x,
        const float* __restrict__ wh, const void* __restrict__ wm_raw,
        const int* __restrict__ wl, const void* __restrict__ hm_raw,
        const void* __restrict__ mm_raw, const float* __restrict__ scale_p,
        unsigned short* __restrict__ wbf, unsigned short* __restrict__ xbf) {
    const int bid = blockIdx.x;
    const int tid = threadIdx.x;

    if (bid >= 8192) {
        const size_t i = ((size_t)(bid - 8192) * 256 + tid) * 8;
        floatx4 f0 = *(const floatx4*)(x + i);
        floatx4 f1 = *(const floatx4*)(x + i + 4);
        short8 s;
        s[0] = (short)f2bf(f0[0]); s[1] = (short)f2bf(f0[1]);
        s[2] = (short)f2bf(f0[2]); s[3] = (short)f2bf(f0[3]);
        s[4] = (short)f2bf(f1[0]); s[5] = (short)f2bf(f1[1]);
        s[6] = (short)f2bf(f1[2]); s[7] = (short)f2bf(f1[3]);
        *(short8*)(xbf + i) = s;
        return;
    }

    // dtype flags from the first 64 words (L2 broadcast, per-block ballot)
    const int lane = tid & 63;
    union { unsigned u; float f; } pw; pw.u = ((const unsigned*)wm_raw)[lane];
    const float pav = fabsf(pw.f);
    const bool wm_f32  = __popcll(__ballot(pav > 1e-4f && pav < 1.0f)) >= 4;
    const bool mask_u8 = __ballot(((const unsigned*)hm_raw)[lane] > 1u) != 0;

    const size_t i = ((size_t)bid * 256 + tid) * 8;
    const float scale = *scale_p;

    floatx4 h0 = *(const floatx4*)(wh + i);
    floatx4 h1 = *(const floatx4*)(wh + i + 4);
    intx4  l0 = *(const intx4*)(wl + i);
    intx4  l1 = *(const intx4*)(wl + i + 4);

    float mv[8];
    if (wm_f32) {
        floatx4 m0 = *(const floatx4*)((const float*)wm_raw + i);
        floatx4 m1 = *(const floatx4*)((const float*)wm_raw + i + 4);
#pragma unroll
        for (int e = 0; e < 4; ++e) { mv[e] = m0[e]; mv[e + 4] = m1[e]; }
    } else {
        half8 m = *(const half8*)((const _Float16*)wm_raw + i);
#pragma unroll
        for (int e = 0; e < 8; ++e) mv[e] = (float)m[e];
    }

    int lowmask[8];
    if (mask_u8) {
        uchar8 a = *(const uchar8*)((const unsigned char*)hm_raw + i);
        uchar8 b = *(const uchar8*)((const unsigned char*)mm_raw + i);
#pragma unroll
        for (int e = 0; e < 8; ++e) lowmask[e] = (a[e] | b[e]) == 0;
    } else {
        intx4 a0 = *(const intx4*)((const int*)hm_raw + i);
        intx4 a1 = *(const intx4*)((const int*)hm_raw + i + 4);
        intx4 b0 = *(const intx4*)((const int*)mm_raw + i);
        intx4 b1 = *(const intx4*)((const int*)mm_raw + i + 4);
#pragma unroll
        for (int e = 0; e < 4; ++e) {
            lowmask[e]     = (a0[e] | b0[e]) == 0;
            lowmask[e + 4] = (a1[e] | b1[e]) == 0;
        }
    }

    short8 s;
#pragma unroll
    for (int e = 0; e < 8; ++e) {
        float v = (e < 4 ? h0[e] : h1[e - 4]) + mv[e];
        int   lw = (e < 4 ? l0[e] : l1[e - 4]);
        if (lowmask[e]) v += (float)lw * scale;
        s[e] = (short)f2bf(v);
    }
    *(short8*)(wbf + i) = s;
}

// ---------- 256x256 GEMM, BK=32, 4-buffer counted-vmcnt, reads 1 tile ahead ----------
// C[m,n] = sum_k A[m,k]*B[n,k] + bias[n] (A,B bf16 row-major [*,K], C fp32)
// 512 threads = 8 waves (2M x 4N); per-wave output 128x64.
// LDS: 4 buffers x (A 16KB + B 16KB) = 128 KiB dynamic, 1 block/CU.
// VMEM ledger: 4 stage-loads/thread/tile; at iter-t top outstanding =
// [stage(t+1)x4, stage(t+2)x4]; WAITV(4) drains stage(t+1) -> tile t+1 is
// published by the barrier ONE ITER EARLY, so reads(t+1) may issue in iter t.
// DS ledger: at iter t, outstanding = reads(t)x12 (from iter t-1) + reads(t+1)x12
// (this iter); lgkmcnt(12) waits only reads(t); reads(t+1) drain under MFMA(t).
// Clobber proof: reads(t-1) lgkm-drained in iter t-1 before MFMA(t-1); BAR(t)
// postdates that for all waves; stage(t+3)->buf[(t-1)&3] issues after BAR(t).
__global__ __launch_bounds__(512, 2) void gemm256_kernel(
        const unsigned short* __restrict__ A,   // [M,K] bf16
        const unsigned short* __restrict__ Bw,  // [N,K] bf16
        const float* __restrict__ bias,
        float* __restrict__ out) {
    extern __shared__ char smem[];
    const int tid  = threadIdx.x;
    const int wave = tid >> 6, lane = tid & 63;
    const int lrow = lane & 15, lquad = lane >> 4;

    // XCD-bijective swizzle: 512 blocks, 64 per XCD; bn varies fastest within
    // an XCD so co-resident blocks share the A panel in L2.
    const int wg  = blockIdx.x;
    const int swz = (wg & 7) * 64 + (wg >> 3);
    const int bm0 = (swz >> 4) * 256;   // 32 row-tiles
    const int bn0 = (swz & 15) * 256;   // 16 col-tiles

    const int wr = wave >> 2, wc = wave & 3;
    const int wm = wr * 128, wn = wc * 64;

    // staging: linear LDS dest, pre-swizzled per-lane global source
    const int lane2 = lane ^ ((lane & 32) ? 2 : 0);
    const int srow  = wave * 16 + (lane2 >> 2);   // 0..127
    const int scol  = (lane2 & 3) * 8;            // 0,8,16,24
    const unsigned short* gA0 = A  + (size_t)(bm0 + srow) * K_DIM + scol;
    const unsigned short* gA1 = gA0 + (size_t)128 * K_DIM;
    const unsigned short* gB0 = Bw + (size_t)(bn0 + srow) * K_DIM + scol;
    const unsigned short* gB1 = gB0 + (size_t)128 * K_DIM;
    const int dstS = wave * 1024;   // wave-uniform LDS byte offset

    // swizzled LDS read byte offsets (A at +0, B at +16384 within a buffer)
    int offA[8], offB[4];
#pragma unroll
    for (int i = 0; i < 8; ++i) {
        int q = (wm + i * 16 + lrow) * 64 + lquad * 16;
        offA[i] = q ^ (((q >> 9) & 1) << 5);
    }
#pragma unroll
    for (int j = 0; j < 4; ++j) {
        int q = (wn + j * 16 + lrow) * 64 + lquad * 16;
        offB[j] = 16384 + (q ^ (((q >> 9) & 1) << 5));
    }

    floatx4 acc[8][4] = {};
    short8 afX[8], bqX[4], afY[8], bqY[4];   // double-buffered fragment regs

#define STAGE(T) do { \
        char* d_ = smem + ((T) & 3) * 32768 + dstS; \
        const unsigned ko_ = (unsigned)(T) * 32u; \
        async16(gA0 + ko_, d_); async16(gA1 + ko_, d_ + 8192); \
        async16(gB0 + ko_, d_ + 16384); async16(gB1 + ko_, d_ + 24576); } while (0)

#define RDS(AF, BQ, T) do { \
        const char* ab_ = smem + ((T) & 3) * 32768; \
        _Pragma("unroll") \
        for (int i_ = 0; i_ < 8; ++i_) AF[i_] = *(const short8*)(ab_ + offA[i_]); \
        _Pragma("unroll") \
        for (int j_ = 0; j_ < 4; ++j_) BQ[j_] = *(const short8*)(ab_ + offB[j_]); \
    } while (0)

#define MMA(AF, BQ) do { \
        __builtin_amdgcn_s_setprio(1); \
        _Pragma("unroll") \
        for (int i_ = 0; i_ < 8; ++i_) \
            _Pragma("unroll") \
            for (int j_ = 0; j_ < 4; ++j_) \
                acc[i_][j_] = __builtin_amdgcn_mfma_f32_16x16x32_bf16(AF[i_], BQ[j_], acc[i_][j_], 0, 0, 0); \
        __builtin_amdgcn_s_setprio(0); } while (0)

#define WAITV(n) asm volatile("s_waitcnt vmcnt(" #n ")" ::: "memory")
#define LGKM(n)  asm volatile("s_waitcnt lgkmcnt(" #n ")" ::: "memory")
#define BAR() do { __builtin_amdgcn_s_barrier(); asm volatile("" ::: "memory"); } while (0)
#define SCHED0() __builtin_amdgcn_sched_barrier(0)

// iter t: MFMA consumes (AFC,BQC) = reads(t) issued last iter; reads(t+1) go
// into (AFN,BQN) and drain under the MFMA. lgkmcnt(12) separates the two sets.
#define ITER(T, AFC, BQC, AFN, BQN, DOB) do { \
        WAITV(4); \
        BAR(); \
        if (DOB) STAGE((T) + 3); \
        RDS(AFN, BQN, (T) + 1); \
        LGKM(12); \
        SCHED0(); \
        MMA(AFC, BQC); } while (0)

    // prologue: stage tiles 0..2 (12 vmem), publish tile 0, issue reads(0)
    STAGE(0); STAGE(1); STAGE(2);
    WAITV(8);               // drain stage(0); [stage(1),stage(2)] = 8 left
    BAR();                  // tile 0 published
    RDS(afX, bqX, 0);       // reads(0) in flight (12 ds ops)

    const int NT = K_DIM / 32;  // 128
    // main: t = 0..123 paired (X/Y alternation), stages t+3 <= 126
    for (int t = 0; t < NT - 4; t += 2) {
        ITER(t,     afX, bqX, afY, bqY, true);
        ITER(t + 1, afY, bqY, afX, bqX, true);
    }
    // t = 124: stage(127), reads(125)->Y, MFMA X(124)
    ITER(NT - 4, afX, bqX, afY, bqY, true);
    // t = 125: outstanding stages [126,127]; WAITV(4) drains 126; reads(126)->X
    ITER(NT - 3, afY, bqY, afX, bqX, false);
    // t = 126: outstanding stage(127)x4 -> WAITV(0); reads(127)->Y; MFMA X(126)
    WAITV(0); BAR(); RDS(afY, bqY, NT - 1); LGKM(12); SCHED0(); MMA(afX, bqX);
    // t = 127: drain remaining reads, final MFMA
    LGKM(0); SCHED0(); MMA(afY, bqY);

#undef STAGE
#undef RDS
#undef MMA
#undef WAITV
#undef LGKM
#undef BAR
#undef SCHED0
#undef ITER

    // epilogue (verified 16x16 C/D layout: col = lane&15, row = lquad*4 + r)
#pragma unroll
    for (int j = 0; j < 4; ++j) {
        const int col = bn0 + wn + j * 16 + lrow;
        const float bv = bias[col];
#pragma unroll
        for (int i = 0; i < 8; ++i) {
            const int row = bm0 + wm + i * 16 + lquad * 4;
#pragma unroll
            for (int r = 0; r < 4; ++r)
                out[(size_t)(row + r) * N_DIM + col] = acc[i][j][r] + bv;
        }
    }
}

// ---------- fallback: A staged from fp32 inline (small-ws path) ----------
__global__ __launch_bounds__(256) void gemm_fused_kernel(
        const float* __restrict__ X,            // [M,K] fp32
        const unsigned short* __restrict__ Bw,  // [N,K] bf16
        const float* __restrict__ bias,
        float* __restrict__ out) {
    __shared__ unsigned short As[128 * 32];
    __shared__ unsigned short Bs[128 * 32];
    const int tid  = threadIdx.x;
    const int wave = tid >> 6, lane = tid & 63;
    const int bm0 = blockIdx.y * 128, bn0 = blockIdx.x * 128;
    const int wm = (wave >> 1) * 64, wn = (wave & 1) * 64;
    const int lrow = lane & 15, lquad = lane >> 4;
    const int arow = tid >> 1, acol = (tid & 1) * 16;

    floatx4 acc[4][4] = {};

    for (int k0 = 0; k0 < K_DIM; k0 += 32) {
        __syncthreads();
#pragma unroll
        for (int c = 0; c < 2; ++c) {
            const int lb  = wave * 2048 + c * 1024;
            const int e   = (lb >> 1) + lane * 8;
            const int row = e >> 5, col = e & 31;
            async16(Bw + (size_t)(bn0 + row) * K_DIM + k0 + col, (const char*)Bs + lb);
        }
        {
            const float* g = X + (size_t)(bm0 + arow) * K_DIM + k0 + acol;
            floatx4 f0 = *(const floatx4*)(g);
            floatx4 f1 = *(const floatx4*)(g + 4);
            floatx4 f2 = *(const floatx4*)(g + 8);
            floatx4 f3 = *(const floatx4*)(g + 12);
            short8 s0, s1;
            s0[0]=(short)f2bf(f0[0]); s0[1]=(short)f2bf(f0[1]); s0[2]=(short)f2bf(f0[2]); s0[3]=(short)f2bf(f0[3]);
            s0[4]=(short)f2bf(f1[0]); s0[5]=(short)f2bf(f1[1]); s0[6]=(short)f2bf(f1[2]); s0[7]=(short)f2bf(f1[3]);
            s1[0]=(short)f2bf(f2[0]); s1[1]=(short)f2bf(f2[1]); s1[2]=(short)f2bf(f2[2]); s1[3]=(short)f2bf(f2[3]);
            s1[4]=(short)f2bf(f3[0]); s1[5]=(short)f2bf(f3[1]); s1[6]=(short)f2bf(f3[2]); s1[7]=(short)f2bf(f3[3]);
            *(short8*)&As[arow * 32 + acol]     = s0;
            *(short8*)&As[arow * 32 + acol + 8] = s1;
        }
        __syncthreads();

        short8 af[4], bf[4];
#pragma unroll
        for (int i = 0; i < 4; ++i)
            af[i] = *(const short8*)&As[(wm + i * 16 + lrow) * 32 + lquad * 8];
#pragma unroll
        for (int j = 0; j < 4; ++j)
            bf[j] = *(const short8*)&Bs[(wn + j * 16 + lrow) * 32 + lquad * 8];
#pragma unroll
        for (int i = 0; i < 4; ++i)
#pragma unroll
            for (int j = 0; j < 4; ++j)
                acc[i][j] = __builtin_amdgcn_mfma_f32_16x16x32_bf16(af[i], bf[j], acc[i][j], 0, 0, 0);
    }

#pragma unroll
    for (int j = 0; j < 4; ++j) {
        const int col = bn0 + wn + j * 16 + lrow;
        const float bv = bias[col];
#pragma unroll
        for (int i = 0; i < 4; ++i) {
            const int row = bm0 + wm + i * 16 + lquad * 4;
#pragma unroll
            for (int r = 0; r < 4; ++r)
                out[(size_t)(row + r) * N_DIM + col] = acc[i][j][r] + bv;
        }
    }
}

extern "C" void kernel_launch(void* const* d_in, const int* in_sizes, int n_in,
                              void* d_out, int out_size, void* d_ws, size_t ws_size,
                              hipStream_t stream) {
    const float*    x     = (const float*)d_in[0];
    const float*    wh    = (const float*)d_in[1];
    const void*     wmed  = d_in[2];           // fp32 or fp16 — detected on device
    const int*      wl    = (const int*)d_in[3];
    const void*     hm    = d_in[4];           // int32 or uint8 — detected on device
    const void*     mm    = d_in[5];
    const float*    scale = (const float*)d_in[6];
    const float*    bias  = (const float*)d_in[7];
    float*          out   = (float*)d_out;

    unsigned short* wbf   = (unsigned short*)((char*)d_ws + 256);         // 32 MB
    unsigned short* xbf   = (unsigned short*)((char*)d_ws + 256 + (size_t)N_DIM * K_DIM * 2);
    const size_t need_full = 256 + (size_t)N_DIM * K_DIM * 2 + (size_t)M_DIM * K_DIM * 2;

    static bool attr_done = false;
    if (!attr_done) {
        (void)hipFuncSetAttribute(reinterpret_cast<const void*>(gemm256_kernel),
                                  hipFuncAttributeMaxDynamicSharedMemorySize, 131072);
        attr_done = true;
    }

    if (ws_size >= need_full) {
        // one fused prep launch: blocks [0,8192) build w, [8192,24576) convert x
        prep_kernel<<<24576, 256, 0, stream>>>(x, wh, wmed, wl, hm, mm, scale, wbf, xbf);
        gemm256_kernel<<<dim3(512), dim3(512), 131072, stream>>>(xbf, wbf, bias, out);
    } else {
        prep_kernel<<<8192, 256, 0, stream>>>(x, wh, wmed, wl, hm, mm, scale, wbf, wbf);
        dim3 grid(N_DIM / 128, M_DIM / 128);
        gemm_fused_kernel<<<grid, 256, 0, stream>>>(x, wbf, bias, out);
    }
}